// Round 17
// baseline (709.876 us; speedup 1.0000x reference)
//
#include <hip/hip_runtime.h>
#include <math.h>

#define NN 2304
#define BB 16
#define CC 256
#define DI 512
#define MM (BB*NN)   // 36864

typedef __attribute__((ext_vector_type(8))) short bf16x8;
typedef __attribute__((ext_vector_type(4))) float f32x4;

__device__ inline unsigned short f2b(float f){
  unsigned u = __float_as_uint(f);
  u = u + 0x7FFFu + ((u>>16)&1u);
  return (unsigned short)(u>>16);
}
__device__ inline float b2f(unsigned short s){ return __uint_as_float(((unsigned)s)<<16); }
__device__ __forceinline__ int dstep(int d){ return (d==0)?-48:(d==1)?48:(d==2)?-1:1; }

// ---------------- merged weight prep ----------------
__global__ __launch_bounds__(256) void k_prep(const float* __restrict__ W_in, const float* __restrict__ W_out,
    const float* __restrict__ fc1_w, const float* __restrict__ fc2_w, const float* __restrict__ W_xp,
    unsigned short* __restrict__ WinT, unsigned short* __restrict__ WoutT,
    unsigned short* __restrict__ fc1T, unsigned short* __restrict__ fc2T, float* __restrict__ WxpT)
{
  int idx = blockIdx.x*256 + threadIdx.x;
  if (idx < 262144){ int r=idx>>10, c=idx&1023; WinT[(size_t)c*256 + r] = f2b(W_in[idx]); return; }
  idx -= 262144;
  if (idx < 131072){ int r=idx>>8, c=idx&255; WoutT[(size_t)c*512 + r] = f2b(W_out[idx]); return; }
  idx -= 131072;
  if (idx < 262144){ int r=idx>>10, c=idx&1023; fc1T[(size_t)c*256 + r] = f2b(fc1_w[idx]); return; }
  idx -= 262144;
  if (idx < 262144){ int r=idx>>8, c=idx&255; fc2T[(size_t)c*1024 + r] = f2b(fc2_w[idx]); return; }
  idx -= 262144;
  if (idx < 9216){ int r=idx/18, c=idx-r*18; WxpT[(size_t)c*512 + r] = W_xp[idx]; }
}

// ---------------- fused feature-norm + LayerNorm ----------------
__global__ __launch_bounds__(256) void k_normln(const float* __restrict__ xin, const float* __restrict__ g,
    const float* __restrict__ bta, float* __restrict__ innorm, unsigned short* __restrict__ outb)
{
  int row = blockIdx.x*4 + (threadIdx.x>>6); int lane=threadIdx.x&63;
  float4 v = *(const float4*)(xin + (size_t)row*CC + lane*4);
  float sq = v.x*v.x + v.y*v.y + v.z*v.z + v.w*v.w;
  float s  = v.x+v.y+v.z+v.w;
  #pragma unroll
  for (int o=32;o;o>>=1){ sq += __shfl_xor(sq,o); s += __shfl_xor(s,o); }
  if (lane==0) innorm[row] = 1.0f/(sqrtf(sq)+1e-8f);
  float m = s*(1.0f/256.0f);
  float dx=v.x-m, dy=v.y-m, dz=v.z-m, dw=v.w-m;
  float ss=dx*dx+dy*dy+dz*dz+dw*dw;
  #pragma unroll
  for (int o=32;o;o>>=1) ss += __shfl_xor(ss,o);
  float rs = rsqrtf(ss*(1.0f/256.0f)+1e-5f);
  int cb=lane*4;
  unsigned o0 = (unsigned)f2b(dx*rs*g[cb+0]+bta[cb+0]) | ((unsigned)f2b(dy*rs*g[cb+1]+bta[cb+1])<<16);
  unsigned o1 = (unsigned)f2b(dz*rs*g[cb+2]+bta[cb+2]) | ((unsigned)f2b(dw*rs*g[cb+3]+bta[cb+3])<<16);
  *(uint2*)(outb + (size_t)row*CC + cb) = make_uint2(o0,o1);
}

// ---------------- edge weights exp(1-cos) ----------------
__global__ __launch_bounds__(256) void k_edge(const float* __restrict__ x, const float* __restrict__ innorm, float* __restrict__ wgt){
  int g = blockIdx.x*4 + (threadIdx.x>>6); int lane = threadIdx.x&63;
  int b = g/NN, n = g - b*NN;
  int r = n/48, c = n - (n/48)*48;
  const float* xb = x + ((size_t)b*NN)*CC;
  float4 vu = *(const float4*)(xb + (size_t)n*CC + lane*4);
  int nb0=(r>0)?n-48:-1, nb1=(r<47)?n+48:-1, nb2=(c>0)?n-1:-1, nb3=(c<47)?n+1:-1;
  float d0=0,d1=0,d2=0,d3=0;
  if (nb0>=0){ float4 t=*(const float4*)(xb+(size_t)nb0*CC+lane*4); d0=vu.x*t.x+vu.y*t.y+vu.z*t.z+vu.w*t.w; }
  if (nb1>=0){ float4 t=*(const float4*)(xb+(size_t)nb1*CC+lane*4); d1=vu.x*t.x+vu.y*t.y+vu.z*t.z+vu.w*t.w; }
  if (nb2>=0){ float4 t=*(const float4*)(xb+(size_t)nb2*CC+lane*4); d2=vu.x*t.x+vu.y*t.y+vu.z*t.z+vu.w*t.w; }
  if (nb3>=0){ float4 t=*(const float4*)(xb+(size_t)nb3*CC+lane*4); d3=vu.x*t.x+vu.y*t.y+vu.z*t.z+vu.w*t.w; }
  #pragma unroll
  for (int o=32;o;o>>=1){ d0+=__shfl_xor(d0,o); d1+=__shfl_xor(d1,o); d2+=__shfl_xor(d2,o); d3+=__shfl_xor(d3,o); }
  if (lane==0){
    float inu = innorm[g];
    float inf_ = __uint_as_float(0x7F800000u);
    float4 w;
    w.x = (nb0>=0)? expf(1.0f - d0*(inu*innorm[g-n+nb0])) : inf_;
    w.y = (nb1>=0)? expf(1.0f - d1*(inu*innorm[g-n+nb1])) : inf_;
    w.z = (nb2>=0)? expf(1.0f - d2*(inu*innorm[g-n+nb2])) : inf_;
    w.w = (nb3>=0)? expf(1.0f - d3*(inu*innorm[g-n+nb3])) : inf_;
    *(float4*)(wgt + (size_t)g*4) = w;
  }
}

// ---------------- MST: Boruvka + Euler-tour rooting; LDS 49.5 KB (hist/par alias dead pk) ----------------
#define INFB 0x7F800000u
#define NILA 0x3FFFu
__device__ void mst_body(unsigned char* smem, const float* __restrict__ wgt, int b,
    unsigned short* __restrict__ parpos_g, int* __restrict__ lvlorder,
    int* __restrict__ lvlstart, int* __restrict__ nlvl)
{
  unsigned* tmask = (unsigned*)smem;                       // [0,9216)
  unsigned* pk    = (unsigned*)(smem + 9216);              // [9216,46080)
  unsigned* comp   = pk;                                   // Boruvka aliases
  unsigned* bestw  = pk + 2304;
  unsigned* bestid = pk + 4608;
  unsigned short* dpos  = (unsigned short*)(smem + 46080); // [46080,50688)
  int* ctr  = (int*)(smem + 50688);                        // [50688,50704)
  int* hist = (int*)pk;                                    // aliases pk[0..2304) AFTER pk dead
  unsigned short* par = (unsigned short*)(pk + 2304);      // aliases pk[2304..3456) AFTER pk dead
  const int tid = threadIdx.x;
  const float* wb = wgt + (size_t)b*NN*4;

  // ======== Boruvka ========
  #pragma unroll
  for (int k=0;k<9;k++){ int v=tid+k*256; comp[v]=v; tmask[v]=0u; }
  __syncthreads();

  for (int round=0; round<14; round++){
    #pragma unroll
    for (int k=0;k<9;k++){ int v=tid+k*256; bestw[v]=INFB; bestid[v]=0xFFFFFFFFu; }
    __syncthreads();
    unsigned candw[9], candi[9];
    #pragma unroll
    for (int k=0;k<9;k++){
      int v=tid+k*256;
      unsigned cv=comp[v];
      int r=v/48, c=v-(v/48)*48;
      float4 w4 = *(const float4*)(wb + (size_t)v*4);
      unsigned cw=INFB, ci=0xFFFFFFFFu;
      if (r>0  && comp[v-48]!=cv){ unsigned wv=__float_as_uint(w4.x); if (wv<cw){cw=wv;ci=(unsigned)(v*4+0);} }
      if (r<47 && comp[v+48]!=cv){ unsigned wv=__float_as_uint(w4.y); if (wv<cw){cw=wv;ci=(unsigned)(v*4+1);} }
      if (c>0  && comp[v-1] !=cv){ unsigned wv=__float_as_uint(w4.z); if (wv<cw){cw=wv;ci=(unsigned)(v*4+2);} }
      if (c<47 && comp[v+1] !=cv){ unsigned wv=__float_as_uint(w4.w); if (wv<cw){cw=wv;ci=(unsigned)(v*4+3);} }
      candw[k]=cw; candi[k]=ci;
      if (cw!=INFB) atomicMin(&bestw[cv], cw);
    }
    __syncthreads();
    #pragma unroll
    for (int k=0;k<9;k++){
      if (candw[k]!=INFB){
        int v=tid+k*256; unsigned cv=comp[v];
        if (bestw[cv]==candw[k]) atomicMin(&bestid[cv], candi[k]);
      }
    }
    __syncthreads();
    unsigned hookS[9];
    int hooked = 0;
    #pragma unroll
    for (int k=0;k<9;k++){
      int v=tid+k*256; hookS[k]=0xFFFFFFFFu;
      if (comp[v]!=(unsigned)v) continue;
      unsigned id=bestid[v];
      if (id==0xFFFFFFFFu) continue;
      int u=(int)(id>>2), d=(int)(id&3);
      int o = u + dstep(d);
      unsigned s = comp[o];
      unsigned sid = bestid[s];
      bool mutual=false;
      if (sid!=0xFFFFFFFFu){
        int su=(int)(sid>>2), sd=(int)(sid&3);
        int so = su + dstep(sd);
        mutual = (comp[so]==(unsigned)v);
      }
      if (!mutual || (unsigned)v>s){ hookS[k]=s; hooked=1; }
    }
    __syncthreads();
    #pragma unroll
    for (int k=0;k<9;k++){
      if (hookS[k]==0xFFFFFFFFu) continue;
      int v=tid+k*256;
      unsigned id=bestid[v];
      int u=(int)(id>>2), d=(int)(id&3);
      int o = u + dstep(d);
      comp[v]=hookS[k];
      atomicOr(&tmask[u], 1u<<d);
      atomicOr(&tmask[o], 1u<<(d^1));
    }
    if (__syncthreads_count(hooked)==0) break;
    for (int it=0; it<16; it++){
      int ch=0;
      #pragma unroll
      for (int k=0;k<9;k++){
        int v=tid+k*256;
        unsigned c1=comp[v], c2=comp[c1];
        if (c1!=c2){ comp[v]=c2; ch=1; }
      }
      if (__syncthreads_count(ch)==0) break;
    }
  }
  __syncthreads();   // tmask final; pk region reusable

  // ======== Euler tour rooting ========
  int a0;
  { unsigned m0 = tmask[0]; a0 = __ffs((int)(m0&0xFu))-1; }

  for (int pass=0; pass<2; pass++){
    for (int k=0;k<36;k++){
      int a = k*256+tid;
      int v = a>>2, d = a&3;
      unsigned mv = tmask[v];
      unsigned sc = NILA;
      unsigned vl = pass ? 8192u : 0u;
      if ((mv>>d)&1u){
        int w = v + dstep(d);
        unsigned mw = tmask[w];
        int rd = d^1;
        int nd = -1;
        #pragma unroll
        for (int kk=1;kk<=4;kk++){ int c2=(rd+kk)&3; if (nd<0 && ((mw>>c2)&1u)) nd=c2; }
        sc = (unsigned)(w*4+nd);
        if (sc==(unsigned)a0) sc=NILA;
        vl = pass ? (8192u + (((mv>>(4+d))&1u)? 1u : (unsigned)-1)) : 1u;
      }
      pk[a] = (sc<<14) | (vl & 0x3FFFu);
    }
    __syncthreads();
    for (int it=0; it<13; it++){
      unsigned stg[36];
      #pragma unroll
      for (int k=0;k<36;k++){
        int a=k*256+tid;
        unsigned mine=pk[a];
        unsigned s=mine>>14;
        if (s==NILA) stg[k]=mine;
        else {
          unsigned oth=pk[s];
          unsigned nv=(mine&0x3FFFu)+(oth&0x3FFFu);
          if (pass) nv -= 8192u;
          stg[k]=((oth>>14)<<14)|(nv&0x3FFFu);
        }
      }
      __syncthreads();
      #pragma unroll
      for (int k=0;k<36;k++) pk[k*256+tid]=stg[k];
      __syncthreads();
    }
    if (pass==0){
      // classify down-arcs -> flag only (par derived later, after pk dies)
      for (int k=0;k<36;k++){
        int a=k*256+tid;
        int v=a>>2, d=a&3;
        if ((tmask[v]>>d)&1u){
          int w=v+dstep(d);
          int ra=w*4+(d^1);
          if ((pk[a]&0x3FFFu) > (pk[ra]&0x3FFFu)){
            atomicOr(&tmask[v], 16u<<d);
          }
        }
      }
      __syncthreads();
    }
  }
  if (tid==0){ dpos[0]=0; ctr[3]=0; }
  __syncthreads();
  // depth extraction: LAST reads of pk
  for (int k=0;k<36;k++){
    int a=k*256+tid;
    int v=a>>2, d=a&3;
    unsigned mv=tmask[v];
    if (((mv>>d)&1u) && ((mv>>(4+d))&1u)){
      int w=v+dstep(d);
      int S=(int)(pk[a]&0x3FFFu)-8192;
      int dep=1-S;
      dpos[w]=(unsigned short)dep;
      atomicMax(&ctr[3],dep);
    }
  }
  __syncthreads();   // pk dead: hist/par may now overwrite it
  int nlv_=ctr[3]+1;
  for (int i=tid;i<nlv_;i+=256) hist[i]=0;
  // derive par from tmask down-flags (into pk-aliased region)
  for (int k=0;k<36;k++){
    int a=k*256+tid;
    int v=a>>2, d=a&3;
    unsigned mv=tmask[v];
    if (((mv>>d)&1u) && ((mv>>(4+d))&1u)) par[v+dstep(d)]=(unsigned short)v;
  }
  if (tid==0) par[0]=0;
  __syncthreads();
  for (int i=tid;i<NN;i+=256) atomicAdd(&hist[dpos[i]],1);
  __syncthreads();
  if (tid==0){
    int run=0;
    for (int l=0;l<nlv_;l++){ int c2=hist[l]; hist[l]=run; lvlstart[b*(NN+2)+l]=run; run+=c2; }
    lvlstart[b*(NN+2)+nlv_]=run;
    nlvl[b]=nlv_;
  }
  __syncthreads();
  for (int i=tid;i<NN;i+=256){
    int pos=atomicAdd(&hist[dpos[i]],1);
    lvlorder[b*NN+pos]=i;
    dpos[i]=(unsigned short)pos;
  }
  __syncthreads();
  for (int i=tid;i<NN;i+=256)
    parpos_g[b*NN + dpos[i]] = dpos[par[i]];
}

// ---------------- bf16 MFMA GEMM body, 128x128 tile, BK=32 reg-staged (proven) ----------------
// EPI 0: silu-split. EPI 1: dense residual-add (f32). EPI 2: gelu.
// EPI 3: bout0[row] = bf16(addin_f32[grow] + acc)  (gather residual, bf16 out)
// EPI 4: fout[grow] = b2f(bout1[row]) + acc        (scatter out, bf16 addin)
template<int EPI>
__device__ void gemm_body(unsigned short* lA, unsigned short* lB, int bm, int bn,
    const unsigned short* __restrict__ A, const unsigned short* __restrict__ BT,
    const float* __restrict__ bias, int Ndim, int K,
    const float* __restrict__ addin, float* __restrict__ fout,
    unsigned short* __restrict__ bout0, unsigned short* __restrict__ bout1,
    const int* __restrict__ lvl)
{
  int tid=threadIdx.x, wid=tid>>6, lane=tid&63;
  const unsigned short* Ab = A + (size_t)bm*128*K;
  const unsigned short* Bb = BT + (size_t)bn*128*K;
  int wr=wid>>1, wc=wid&1;
  f32x4 acc[4][4];
  #pragma unroll
  for (int m2=0;m2<4;m2++)
    #pragma unroll
    for (int n2=0;n2<4;n2++)
      #pragma unroll
      for (int j=0;j<4;j++) acc[m2][n2][j]=0.f;
  int r0 = tid>>2, c0 = (tid&3)*8;
  for (int k0=0;k0<K;k0+=32){
    int4 va0 = *(const int4*)(Ab + (size_t)r0*K + k0 + c0);
    int4 va1 = *(const int4*)(Ab + (size_t)(r0+64)*K + k0 + c0);
    int4 vb0 = *(const int4*)(Bb + (size_t)r0*K + k0 + c0);
    int4 vb1 = *(const int4*)(Bb + (size_t)(r0+64)*K + k0 + c0);
    __syncthreads();
    *(int4*)(lA + r0*32 + c0) = va0;
    *(int4*)(lA + (r0+64)*32 + c0) = va1;
    *(int4*)(lB + r0*32 + c0) = vb0;
    *(int4*)(lB + (r0+64)*32 + c0) = vb1;
    __syncthreads();
    int ra = (wr<<6) + (lane&15);
    int rb = (wc<<6) + (lane&15);
    int cb = (lane>>4)<<3;
    bf16x8 af[4], bfr[4];
    #pragma unroll
    for (int m2=0;m2<4;m2++) af[m2] = *(const bf16x8*)(lA + (ra+m2*16)*32 + cb);
    #pragma unroll
    for (int n2=0;n2<4;n2++) bfr[n2] = *(const bf16x8*)(lB + (rb+n2*16)*32 + cb);
    #pragma unroll
    for (int m2=0;m2<4;m2++)
      #pragma unroll
      for (int n2=0;n2<4;n2++)
        acc[m2][n2] = __builtin_amdgcn_mfma_f32_16x16x32_bf16(af[m2], bfr[n2], acc[m2][n2], 0,0,0);
  }
  int rr = (lane>>4)<<2, cc = lane&15;
  #pragma unroll
  for (int m2=0;m2<4;m2++){
    #pragma unroll
    for (int n2=0;n2<4;n2++){
      int col = (bn<<7) + (wc<<6) + (n2<<4) + cc;
      float bs = bias[col];
      #pragma unroll
      for (int j=0;j<4;j++){
        int row = (bm<<7) + (wr<<6) + (m2<<4) + rr + j;
        float v = acc[m2][n2][j] + bs;
        if (EPI==0){
          float sv = v * (1.0f/(1.0f+expf(-v)));
          if (col < DI) bout0[(size_t)row*DI + col] = f2b(sv);
          else          bout1[(size_t)row*DI + col - DI] = f2b(sv);
        } else if (EPI==1){
          size_t oi=(size_t)row*Ndim+col;
          fout[oi] = addin[oi] + v;
        } else if (EPI==2){
          size_t oi=(size_t)row*Ndim+col;
          bout0[oi] = f2b(0.5f*v*(1.0f+erff(v*0.70710678118f)));
        } else if (EPI==3){
          int grow = (row/NN)*NN + lvl[row];
          bout0[(size_t)row*Ndim+col] = f2b(addin[(size_t)grow*Ndim+col] + v);
        } else {
          int grow = (row/NN)*NN + lvl[row];
          fout[(size_t)grow*Ndim+col] = b2f(bout1[(size_t)row*Ndim+col]) + v;
        }
      }
    }
  }
}

template<int EPI>
__global__ __launch_bounds__(256) void k_gemm(
    const unsigned short* __restrict__ A, const unsigned short* __restrict__ BT,
    const float* __restrict__ bias, int Ndim, int K,
    const float* __restrict__ addin, float* __restrict__ fout,
    unsigned short* __restrict__ bout0, unsigned short* __restrict__ bout1,
    const int* __restrict__ lvl)
{
  __shared__ __align__(16) unsigned short lAB[128*32*2];
  int ntn = Ndim>>7;
  int bm = blockIdx.x/ntn, bn = blockIdx.x - bm*ntn;
  gemm_body<EPI>(lAB, lAB+128*32, bm, bn, A, BT, bias, Ndim, K, addin, fout, bout0, bout1, lvl);
}

// ---------------- fused: MST (blocks 0-15) + gemm<0> tiles; 49.5 KB LDS -> 3 blocks/CU ----------------
__global__ __launch_bounds__(256) void k_fused(
    const unsigned short* __restrict__ xn, const unsigned short* __restrict__ WinT,
    const float* __restrict__ b_in,
    unsigned short* __restrict__ xi_b, unsigned short* __restrict__ sz_b,
    const float* __restrict__ wgt, unsigned short* __restrict__ parpos_g,
    int* __restrict__ lvlorder, int* __restrict__ lvlstart, int* __restrict__ nlvl)
{
  __shared__ __align__(16) unsigned char smem[50704];
  if (blockIdx.x < BB){
    mst_body(smem, wgt, blockIdx.x, parpos_g, lvlorder, lvlstart, nlvl);
  } else {
    int bid = blockIdx.x - BB;
    int bm = bid>>3, bn = bid&7;
    gemm_body<0>((unsigned short*)smem, (unsigned short*)smem + 128*32, bm, bn,
                 xn, WinT, b_in, 1024, 256, nullptr, nullptr, xi_b, sz_b, nullptr);
  }
}

// ---------------- LayerNorm (bf16 input) -> bf16 ----------------
__global__ __launch_bounds__(256) void k_lnb(const unsigned short* __restrict__ xin, const float* __restrict__ g,
    const float* __restrict__ bta, unsigned short* __restrict__ outb)
{
  int row = blockIdx.x*4 + (threadIdx.x>>6); int lane=threadIdx.x&63;
  uint2 raw = *(const uint2*)(xin + (size_t)row*CC + lane*4);
  float vx=b2f((unsigned short)(raw.x&0xFFFFu)), vy=b2f((unsigned short)(raw.x>>16));
  float vz=b2f((unsigned short)(raw.y&0xFFFFu)), vw=b2f((unsigned short)(raw.y>>16));
  float s = vx+vy+vz+vw;
  #pragma unroll
  for (int o=32;o;o>>=1) s += __shfl_xor(s,o);
  float m = s*(1.0f/256.0f);
  float dx=vx-m, dy=vy-m, dz=vz-m, dw=vw-m;
  float ss=dx*dx+dy*dy+dz*dz+dw*dw;
  #pragma unroll
  for (int o=32;o;o>>=1) ss += __shfl_xor(ss,o);
  float rs = rsqrtf(ss*(1.0f/256.0f)+1e-5f);
  int cb=lane*4;
  unsigned o0 = (unsigned)f2b(dx*rs*g[cb+0]+bta[cb+0]) | ((unsigned)f2b(dy*rs*g[cb+1]+bta[cb+1])<<16);
  unsigned o1 = (unsigned)f2b(dz*rs*g[cb+2]+bta[cb+2]) | ((unsigned)f2b(dw*rs*g[cb+3]+bta[cb+3])<<16);
  *(uint2*)(outb + (size_t)row*CC + cb) = make_uint2(o0,o1);
}

// ---------------- dbc = xi @ W_xp (18 cols), ILP-parallel butterfly ----------------
__global__ __launch_bounds__(256) void k_dbc(const unsigned short* __restrict__ xi_b,
    const float* __restrict__ WxpT, float* __restrict__ dbc)
{
  int row = blockIdx.x*4 + (threadIdx.x>>6); int lane=threadIdx.x&63;
  int4 raw = *(const int4*)(xi_b + (size_t)row*DI + lane*8);
  float xf[8];
  xf[0]=b2f((unsigned short)((unsigned)raw.x&0xFFFFu)); xf[1]=b2f((unsigned short)((unsigned)raw.x>>16));
  xf[2]=b2f((unsigned short)((unsigned)raw.y&0xFFFFu)); xf[3]=b2f((unsigned short)((unsigned)raw.y>>16));
  xf[4]=b2f((unsigned short)((unsigned)raw.z&0xFFFFu)); xf[5]=b2f((unsigned short)((unsigned)raw.z>>16));
  xf[6]=b2f((unsigned short)((unsigned)raw.w&0xFFFFu)); xf[7]=b2f((unsigned short)((unsigned)raw.w>>16));
  float s[18];
  #pragma unroll
  for (int jc=0;jc<18;jc++){
    const float* wr_ = WxpT + (size_t)jc*DI + lane*8;
    float t=0.f;
    #pragma unroll
    for (int q=0;q<8;q++) t += xf[q]*wr_[q];
    s[jc]=t;
  }
  #pragma unroll
  for (int o=32;o;o>>=1){
    #pragma unroll
    for (int jc=0;jc<18;jc++) s[jc] += __shfl_xor(s[jc],o);
  }
  #pragma unroll
  for (int jc=0;jc<18;jc++)
    if (lane==jc) dbc[(size_t)row*18+jc]=s[jc];
}

// ---------------- dt/softplus -> decay/Bx, position-grouped, CHANNEL-MAJOR out ----------------
__global__ __launch_bounds__(512) void k_dbx(const float* __restrict__ dbc, const unsigned short* __restrict__ xi_b,
  const float* __restrict__ W_dt, const float* __restrict__ b_dt, const float* __restrict__ A_log,
  const int* __restrict__ lvlorder,
  unsigned short* __restrict__ dec_cm, unsigned short* __restrict__ bx_cm)
{
  __shared__ int smap[32];
  __shared__ float sd[32][18];
  int c = threadIdx.x;
  int b = blockIdx.x/72, pg = blockIdx.x - b*72;
  int p0 = pg*32;
  if (c<32) smap[c] = b*NN + lvlorder[b*NN + p0 + c];
  __syncthreads();
  for (int i=c;i<32*18;i+=512){ int rr=i/18, q=i-rr*18; sd[rr][q]=dbc[(size_t)smap[rr]*18+q]; }
  __syncthreads();
  float wdt[16];
  #pragma unroll
  for (int r2=0;r2<16;r2++) wdt[r2]=W_dt[r2*DI+c];
  float bd=b_dt[c];
  float nA=-expf(A_log[c]);
  unsigned decp[16], bxp[16];
  #pragma unroll
  for (int rr=0;rr<32;rr++){
    float a=bd;
    #pragma unroll
    for (int r2=0;r2<16;r2++) a += sd[rr][r2]*wdt[r2];
    float dt = (a>20.f)? a : log1pf(expf(a));
    float dec = expf(dt*nA);
    float bx = dt*sd[rr][16]*b2f(xi_b[(size_t)smap[rr]*DI + c]);
    if (rr&1){ decp[rr>>1] |= ((unsigned)f2b(dec))<<16; bxp[rr>>1] |= ((unsigned)f2b(bx))<<16; }
    else     { decp[rr>>1]  =  (unsigned)f2b(dec);      bxp[rr>>1]  =  (unsigned)f2b(bx); }
  }
  size_t chb = ((size_t)b*DI + c)*NN + p0;
  uint4* dp = (uint4*)(dec_cm + chb);
  uint4* bp = (uint4*)(bx_cm + chb);
  #pragma unroll
  for (int q=0;q<4;q++){
    uint4 dv, bv;
    dv.x=decp[q*4+0]; dv.y=decp[q*4+1]; dv.z=decp[q*4+2]; dv.w=decp[q*4+3];
    bv.x=bxp[q*4+0];  bv.y=bxp[q*4+1];  bv.z=bxp[q*4+2];  bv.w=bxp[q*4+3];
    dp[q]=dv; bp[q]=bv;
  }
}

// ---------------- tree scan in position space, channel-major, h in place over bx ----------------
#define SCH 4
__global__ __launch_bounds__(256) void k_scan(const unsigned short* __restrict__ dec_cm,
    unsigned short* __restrict__ bx_cm,
    const unsigned short* __restrict__ parpos_g,
    const int* __restrict__ lvlstart, const int* __restrict__ nlvl)
{
  __shared__ unsigned short sdec[SCH*NN];
  __shared__ unsigned short sbx[SCH*NN];
  __shared__ unsigned short spp[NN];
  int b = blockIdx.x>>7, t = blockIdx.x&127;
  int c0 = t*SCH;
  int tid = threadIdx.x;
  const size_t gch = ((size_t)b*DI + c0)*NN;
  #pragma unroll
  for (int cc=0;cc<SCH;cc++){
    const uint2* gd = (const uint2*)(dec_cm + gch + (size_t)cc*NN);
    const uint2* gb = (const uint2*)(bx_cm + gch + (size_t)cc*NN);
    uint2* ld = (uint2*)(sdec + cc*NN);
    uint2* lb = (uint2*)(sbx + cc*NN);
    for (int i=tid;i<NN/4;i+=256){ ld[i]=gd[i]; lb[i]=gb[i]; }
  }
  for (int i=tid;i<NN;i+=256) spp[i]=parpos_g[b*NN+i];
  int nlv = nlvl[b];
  __syncthreads();
  for (int lvl=1; lvl<nlv; lvl++){
    int s=lvlstart[b*(NN+2)+lvl], e=lvlstart[b*(NN+2)+lvl+1];
    int tot=(e-s)*SCH;
    for (int idx=tid; idx<tot; idx+=256){
      int p = s + (idx>>2);
      int cc = idx&3;
      int pp = spp[p];
      float hv = b2f(sdec[cc*NN+p])*b2f(sbx[cc*NN+pp]) + b2f(sbx[cc*NN+p]);
      sbx[cc*NN+p] = f2b(hv);
    }
    __syncthreads();
  }
  #pragma unroll
  for (int cc=0;cc<SCH;cc++){
    uint2* gb = (uint2*)(bx_cm + gch + (size_t)cc*NN);
    const uint2* lb = (const uint2*)(sbx + cc*NN);
    for (int i=tid;i<NN/4;i+=256) gb[i]=lb[i];
  }
}

// ---------------- u = (Cv*h + Dp*xi)*silu_z -> u_perm [pos][512] ----------------
__global__ __launch_bounds__(512) void k_u(const unsigned short* __restrict__ h_cm,
    const unsigned short* __restrict__ xi_b, const unsigned short* __restrict__ sz_b,
    const float* __restrict__ dbc, const float* __restrict__ Dp,
    const int* __restrict__ lvlorder, unsigned short* __restrict__ u_perm)
{
  __shared__ int smap[32];
  __shared__ unsigned short hT[32*512];
  int c = threadIdx.x;
  int b = blockIdx.x/72, pg = blockIdx.x - b*72;
  int p0 = pg*32;
  if (c<32) smap[c] = b*NN + lvlorder[b*NN + p0 + c];
  {
    const uint4* gh = (const uint4*)(h_cm + ((size_t)b*DI + c)*NN + p0);
    #pragma unroll
    for (int q=0;q<4;q++){
      uint4 w = gh[q];
      unsigned ws[4] = {w.x,w.y,w.z,w.w};
      #pragma unroll
      for (int e=0;e<4;e++){
        hT[(q*8+e*2+0)*512 + c] = (unsigned short)(ws[e]&0xFFFFu);
        hT[(q*8+e*2+1)*512 + c] = (unsigned short)(ws[e]>>16);
      }
    }
  }
  float dpc = Dp[c];
  __syncthreads();
  #pragma unroll 4
  for (int rr=0;rr<32;rr++){
    int grow = smap[rr];
    float Cv = dbc[(size_t)grow*18+17];
    float xiv = b2f(xi_b[(size_t)grow*DI + c]);
    float szv = b2f(sz_b[(size_t)grow*DI + c]);
    float hv = b2f(hT[rr*512 + c]);
    float u = (Cv*hv + dpc*xiv)*szv;
    u_perm[((size_t)(b*NN + p0 + rr))*DI + c] = f2b(u);
  }
}

// ---------------- launch ----------------
extern "C" void kernel_launch(void* const* d_in, const int* in_sizes, int n_in,
                              void* d_out, int out_size, void* d_ws, size_t ws_size,
                              hipStream_t stream) {
  (void)in_sizes; (void)n_in; (void)out_size; (void)ws_size;
  const float* x      = (const float*)d_in[0];
  const float* n1w    = (const float*)d_in[1];
  const float* n1b    = (const float*)d_in[2];
  const float* n2w    = (const float*)d_in[3];
  const float* n2b    = (const float*)d_in[4];
  const float* W_in   = (const float*)d_in[5];
  const float* b_in   = (const float*)d_in[6];
  const float* W_xp   = (const float*)d_in[7];
  const float* W_dt   = (const float*)d_in[8];
  const float* b_dt   = (const float*)d_in[9];
  const float* A_log  = (const float*)d_in[10];
  const float* Dp     = (const float*)d_in[11];
  const float* W_out  = (const float*)d_in[12];
  const float* b_out  = (const float*)d_in[13];
  const float* fc1_w  = (const float*)d_in[14];
  const float* fc1_b  = (const float*)d_in[15];
  const float* fc2_w  = (const float*)d_in[16];
  const float* fc2_b  = (const float*)d_in[17];

  char* base=(char*)d_ws; size_t off=0;
  auto alc=[&](size_t nb)->char*{ char* p=base+off; off=(off+nb+255)&~(size_t)255; return p; };
  float* wgt            = (float*)alc((size_t)MM*4*4);
  float* innorm         = (float*)alc((size_t)MM*4);
  unsigned short* parpos= (unsigned short*)alc((size_t)MM*2);
  int* lvlorder         = (int*)alc((size_t)MM*4);
  int* lvlstart         = (int*)alc((size_t)BB*(NN+2)*4);
  int* nlvl             = (int*)alc((size_t)BB*4);
  unsigned short* xi_b  = (unsigned short*)alc((size_t)MM*DI*2);
  unsigned short* sz_b  = (unsigned short*)alc((size_t)MM*DI*2);
  float* dbc            = (float*)alc((size_t)MM*18*4);
  unsigned short* dec_cm= (unsigned short*)alc((size_t)MM*DI*2);
  unsigned short* bx_cm = (unsigned short*)alc((size_t)MM*DI*2);
  unsigned short* WinT  = (unsigned short*)alc((size_t)CC*1024*2);
  unsigned short* WoutT = (unsigned short*)alc((size_t)DI*CC*2);
  unsigned short* fc1T  = (unsigned short*)alc((size_t)CC*1024*2);
  unsigned short* fc2T  = (unsigned short*)alc((size_t)1024*CC*2);
  float* WxpT           = (float*)alc((size_t)DI*18*4);
  // lifetime aliases:
  unsigned short* xn      = (unsigned short*)dec_cm; // dead before k_dbx writes dec_cm
  unsigned short* h_cm    = bx_cm;                   // scan output in place
  unsigned short* u_perm  = dec_cm;                  // dec dead after k_scan
  unsigned short* x2b     = bx_cm;                   // [MM][256] bf16; h dead after k_u
  unsigned short* x2n_perm= dec_cm;                  // u_perm dead after gemm<3>
  unsigned short* g1_perm = xi_b;                    // spans xi_b+sz_b, dead after k_u

  k_prep<<<dim3(3620),dim3(256),0,stream>>>(W_in, W_out, fc1_w, fc2_w, W_xp,
                                            WinT, WoutT, fc1T, fc2T, WxpT);
  k_normln<<<dim3(MM/4),dim3(256),0,stream>>>(x, n1w, n1b, innorm, xn);
  k_edge<<<dim3(MM/4),dim3(256),0,stream>>>(x, innorm, wgt);

  k_fused<<<dim3(BB + 288*8),dim3(256),0,stream>>>(xn, WinT, b_in, xi_b, sz_b,
                                                   wgt, parpos, lvlorder, lvlstart, nlvl);

  k_dbc<<<dim3(MM/4),dim3(256),0,stream>>>(xi_b, WxpT, dbc);
  k_dbx<<<dim3(MM/32),dim3(512),0,stream>>>(dbc, xi_b, W_dt, b_dt, A_log, lvlorder, dec_cm, bx_cm);
  k_scan<<<dim3(BB*128),dim3(256),0,stream>>>(dec_cm, bx_cm, parpos, lvlstart, nlvl);
  k_u<<<dim3(MM/32),dim3(512),0,stream>>>(h_cm, xi_b, sz_b, dbc, Dp, lvlorder, u_perm);

  k_gemm<3><<<dim3(288*2),dim3(256),0,stream>>>(u_perm, WoutT, b_out, 256, 512,
                                                x, nullptr, x2b, nullptr, lvlorder);
  k_lnb<<<dim3(MM/4),dim3(256),0,stream>>>(x2b, n2w, n2b, x2n_perm);
  k_gemm<2><<<dim3(288*8),dim3(256),0,stream>>>(x2n_perm, fc1T, fc1_b, 1024, 256,
                                                nullptr, nullptr, g1_perm, nullptr, nullptr);
  k_gemm<4><<<dim3(288*2),dim3(256),0,stream>>>(g1_perm, fc2T, fc2_b, 256, 1024,
                                                nullptr, (float*)d_out, nullptr, x2b, lvlorder);
}

// Round 18
// 703.877 us; speedup vs baseline: 1.0085x; 1.0085x over previous
//
#include <hip/hip_runtime.h>
#include <math.h>

#define NN 2304
#define BB 16
#define CC 256
#define DI 512
#define MM (BB*NN)   // 36864

typedef __attribute__((ext_vector_type(8))) short bf16x8;
typedef __attribute__((ext_vector_type(4))) float f32x4;

__device__ inline unsigned short f2b(float f){
  unsigned u = __float_as_uint(f);
  u = u + 0x7FFFu + ((u>>16)&1u);
  return (unsigned short)(u>>16);
}
__device__ inline float b2f(unsigned short s){ return __uint_as_float(((unsigned)s)<<16); }
__device__ __forceinline__ int dstep(int d){ return (d==0)?-48:(d==1)?48:(d==2)?-1:1; }

// ---------------- merged weight prep ----------------
__global__ __launch_bounds__(256) void k_prep(const float* __restrict__ W_in, const float* __restrict__ W_out,
    const float* __restrict__ fc1_w, const float* __restrict__ fc2_w, const float* __restrict__ W_xp,
    unsigned short* __restrict__ WinT, unsigned short* __restrict__ WoutT,
    unsigned short* __restrict__ fc1T, unsigned short* __restrict__ fc2T, float* __restrict__ WxpT)
{
  int idx = blockIdx.x*256 + threadIdx.x;
  if (idx < 262144){ int r=idx>>10, c=idx&1023; WinT[(size_t)c*256 + r] = f2b(W_in[idx]); return; }
  idx -= 262144;
  if (idx < 131072){ int r=idx>>8, c=idx&255; WoutT[(size_t)c*512 + r] = f2b(W_out[idx]); return; }
  idx -= 131072;
  if (idx < 262144){ int r=idx>>10, c=idx&1023; fc1T[(size_t)c*256 + r] = f2b(fc1_w[idx]); return; }
  idx -= 262144;
  if (idx < 262144){ int r=idx>>8, c=idx&255; fc2T[(size_t)c*1024 + r] = f2b(fc2_w[idx]); return; }
  idx -= 262144;
  if (idx < 9216){ int r=idx/18, c=idx-r*18; WxpT[(size_t)c*512 + r] = W_xp[idx]; }
}

// ---------------- fused feature-norm + LayerNorm ----------------
__global__ __launch_bounds__(256) void k_normln(const float* __restrict__ xin, const float* __restrict__ g,
    const float* __restrict__ bta, float* __restrict__ innorm, unsigned short* __restrict__ outb)
{
  int row = blockIdx.x*4 + (threadIdx.x>>6); int lane=threadIdx.x&63;
  float4 v = *(const float4*)(xin + (size_t)row*CC + lane*4);
  float sq = v.x*v.x + v.y*v.y + v.z*v.z + v.w*v.w;
  float s  = v.x+v.y+v.z+v.w;
  #pragma unroll
  for (int o=32;o;o>>=1){ sq += __shfl_xor(sq,o); s += __shfl_xor(s,o); }
  if (lane==0) innorm[row] = 1.0f/(sqrtf(sq)+1e-8f);
  float m = s*(1.0f/256.0f);
  float dx=v.x-m, dy=v.y-m, dz=v.z-m, dw=v.w-m;
  float ss=dx*dx+dy*dy+dz*dz+dw*dw;
  #pragma unroll
  for (int o=32;o;o>>=1) ss += __shfl_xor(ss,o);
  float rs = rsqrtf(ss*(1.0f/256.0f)+1e-5f);
  int cb=lane*4;
  unsigned o0 = (unsigned)f2b(dx*rs*g[cb+0]+bta[cb+0]) | ((unsigned)f2b(dy*rs*g[cb+1]+bta[cb+1])<<16);
  unsigned o1 = (unsigned)f2b(dz*rs*g[cb+2]+bta[cb+2]) | ((unsigned)f2b(dw*rs*g[cb+3]+bta[cb+3])<<16);
  *(uint2*)(outb + (size_t)row*CC + cb) = make_uint2(o0,o1);
}

// ---------------- edge weights exp(1-cos) ----------------
__global__ __launch_bounds__(256) void k_edge(const float* __restrict__ x, const float* __restrict__ innorm, float* __restrict__ wgt){
  int g = blockIdx.x*4 + (threadIdx.x>>6); int lane = threadIdx.x&63;
  int b = g/NN, n = g - b*NN;
  int r = n/48, c = n - (n/48)*48;
  const float* xb = x + ((size_t)b*NN)*CC;
  float4 vu = *(const float4*)(xb + (size_t)n*CC + lane*4);
  int nb0=(r>0)?n-48:-1, nb1=(r<47)?n+48:-1, nb2=(c>0)?n-1:-1, nb3=(c<47)?n+1:-1;
  float d0=0,d1=0,d2=0,d3=0;
  if (nb0>=0){ float4 t=*(const float4*)(xb+(size_t)nb0*CC+lane*4); d0=vu.x*t.x+vu.y*t.y+vu.z*t.z+vu.w*t.w; }
  if (nb1>=0){ float4 t=*(const float4*)(xb+(size_t)nb1*CC+lane*4); d1=vu.x*t.x+vu.y*t.y+vu.z*t.z+vu.w*t.w; }
  if (nb2>=0){ float4 t=*(const float4*)(xb+(size_t)nb2*CC+lane*4); d2=vu.x*t.x+vu.y*t.y+vu.z*t.z+vu.w*t.w; }
  if (nb3>=0){ float4 t=*(const float4*)(xb+(size_t)nb3*CC+lane*4); d3=vu.x*t.x+vu.y*t.y+vu.z*t.z+vu.w*t.w; }
  #pragma unroll
  for (int o=32;o;o>>=1){ d0+=__shfl_xor(d0,o); d1+=__shfl_xor(d1,o); d2+=__shfl_xor(d2,o); d3+=__shfl_xor(d3,o); }
  if (lane==0){
    float inu = innorm[g];
    float inf_ = __uint_as_float(0x7F800000u);
    float4 w;
    w.x = (nb0>=0)? expf(1.0f - d0*(inu*innorm[g-n+nb0])) : inf_;
    w.y = (nb1>=0)? expf(1.0f - d1*(inu*innorm[g-n+nb1])) : inf_;
    w.z = (nb2>=0)? expf(1.0f - d2*(inu*innorm[g-n+nb2])) : inf_;
    w.w = (nb3>=0)? expf(1.0f - d3*(inu*innorm[g-n+nb3])) : inf_;
    *(float4*)(wgt + (size_t)g*4) = w;
  }
}

// ---------------- MST: Boruvka (256 thr, syncthreads_count exits) + Euler-tour rooting ----------------
#define INFB 0x7F800000u
#define NILA 0x3FFFu
__device__ void mst_body(unsigned char* smem, const float* __restrict__ wgt, int b,
    unsigned short* __restrict__ parpos_g, int* __restrict__ lvlorder,
    int* __restrict__ lvlstart, int* __restrict__ nlvl)
{
  unsigned* tmask = (unsigned*)smem;                       // [0,9216)
  unsigned* pk    = (unsigned*)(smem + 9216);              // [9216,46080)
  unsigned* comp   = pk;                                   // Boruvka aliases
  unsigned* bestw  = pk + 2304;
  unsigned* bestid = pk + 4608;
  unsigned short* par   = (unsigned short*)(smem + 46080); // [46080,50688)
  unsigned short* dpos  = (unsigned short*)(smem + 50688); // [50688,55296)
  int* hist = (int*)(smem + 55296);                        // [55296,64512)
  int* ctr  = (int*)(smem + 64512);                        // [64512,64528)
  const int tid = threadIdx.x;
  const float* wb = wgt + (size_t)b*NN*4;

  // ======== Boruvka ========
  #pragma unroll
  for (int k=0;k<9;k++){ int v=tid+k*256; comp[v]=v; tmask[v]=0u; }
  __syncthreads();

  for (int round=0; round<14; round++){
    #pragma unroll
    for (int k=0;k<9;k++){ int v=tid+k*256; bestw[v]=INFB; bestid[v]=0xFFFFFFFFu; }
    __syncthreads();
    unsigned candw[9], candi[9];
    #pragma unroll
    for (int k=0;k<9;k++){
      int v=tid+k*256;
      unsigned cv=comp[v];
      int r=v/48, c=v-(v/48)*48;
      float4 w4 = *(const float4*)(wb + (size_t)v*4);
      unsigned cw=INFB, ci=0xFFFFFFFFu;
      if (r>0  && comp[v-48]!=cv){ unsigned wv=__float_as_uint(w4.x); if (wv<cw){cw=wv;ci=(unsigned)(v*4+0);} }
      if (r<47 && comp[v+48]!=cv){ unsigned wv=__float_as_uint(w4.y); if (wv<cw){cw=wv;ci=(unsigned)(v*4+1);} }
      if (c>0  && comp[v-1] !=cv){ unsigned wv=__float_as_uint(w4.z); if (wv<cw){cw=wv;ci=(unsigned)(v*4+2);} }
      if (c<47 && comp[v+1] !=cv){ unsigned wv=__float_as_uint(w4.w); if (wv<cw){cw=wv;ci=(unsigned)(v*4+3);} }
      candw[k]=cw; candi[k]=ci;
      if (cw!=INFB) atomicMin(&bestw[cv], cw);
    }
    __syncthreads();
    #pragma unroll
    for (int k=0;k<9;k++){
      if (candw[k]!=INFB){
        int v=tid+k*256; unsigned cv=comp[v];
        if (bestw[cv]==candw[k]) atomicMin(&bestid[cv], candi[k]);
      }
    }
    __syncthreads();
    unsigned hookS[9];
    int hooked = 0;
    #pragma unroll
    for (int k=0;k<9;k++){
      int v=tid+k*256; hookS[k]=0xFFFFFFFFu;
      if (comp[v]!=(unsigned)v) continue;
      unsigned id=bestid[v];
      if (id==0xFFFFFFFFu) continue;
      int u=(int)(id>>2), d=(int)(id&3);
      int o = u + dstep(d);
      unsigned s = comp[o];
      unsigned sid = bestid[s];
      bool mutual=false;
      if (sid!=0xFFFFFFFFu){
        int su=(int)(sid>>2), sd=(int)(sid&3);
        int so = su + dstep(sd);
        mutual = (comp[so]==(unsigned)v);
      }
      if (!mutual || (unsigned)v>s){ hookS[k]=s; hooked=1; }
    }
    __syncthreads();
    #pragma unroll
    for (int k=0;k<9;k++){
      if (hookS[k]==0xFFFFFFFFu) continue;
      int v=tid+k*256;
      unsigned id=bestid[v];
      int u=(int)(id>>2), d=(int)(id&3);
      int o = u + dstep(d);
      comp[v]=hookS[k];
      atomicOr(&tmask[u], 1u<<d);
      atomicOr(&tmask[o], 1u<<(d^1));
    }
    if (__syncthreads_count(hooked)==0) break;
    for (int it=0; it<16; it++){
      int ch=0;
      #pragma unroll
      for (int k=0;k<9;k++){
        int v=tid+k*256;
        unsigned c1=comp[v], c2=comp[c1];
        if (c1!=c2){ comp[v]=c2; ch=1; }
      }
      if (__syncthreads_count(ch)==0) break;
    }
  }
  __syncthreads();   // tmask final; pk region reusable

  // ======== Euler tour rooting ========
  int a0;
  { unsigned m0 = tmask[0]; a0 = __ffs((int)(m0&0xFu))-1; }

  for (int pass=0; pass<2; pass++){
    for (int k=0;k<36;k++){
      int a = k*256+tid;
      int v = a>>2, d = a&3;
      unsigned mv = tmask[v];
      unsigned sc = NILA;
      unsigned vl = pass ? 8192u : 0u;
      if ((mv>>d)&1u){
        int w = v + dstep(d);
        unsigned mw = tmask[w];
        int rd = d^1;
        int nd = -1;
        #pragma unroll
        for (int kk=1;kk<=4;kk++){ int c2=(rd+kk)&3; if (nd<0 && ((mw>>c2)&1u)) nd=c2; }
        sc = (unsigned)(w*4+nd);
        if (sc==(unsigned)a0) sc=NILA;
        vl = pass ? (8192u + (((mv>>(4+d))&1u)? 1u : (unsigned)-1)) : 1u;
      }
      pk[a] = (sc<<14) | (vl & 0x3FFFu);
    }
    __syncthreads();
    for (int it=0; it<13; it++){
      unsigned stg[36];
      #pragma unroll
      for (int k=0;k<36;k++){
        int a=k*256+tid;
        unsigned mine=pk[a];
        unsigned s=mine>>14;
        if (s==NILA) stg[k]=mine;
        else {
          unsigned oth=pk[s];
          unsigned nv=(mine&0x3FFFu)+(oth&0x3FFFu);
          if (pass) nv -= 8192u;
          stg[k]=((oth>>14)<<14)|(nv&0x3FFFu);
        }
      }
      __syncthreads();
      #pragma unroll
      for (int k=0;k<36;k++) pk[k*256+tid]=stg[k];
      __syncthreads();
    }
    if (pass==0){
      for (int k=0;k<36;k++){
        int a=k*256+tid;
        int v=a>>2, d=a&3;
        if ((tmask[v]>>d)&1u){
          int w=v+dstep(d);
          int ra=w*4+(d^1);
          if ((pk[a]&0x3FFFu) > (pk[ra]&0x3FFFu)){
            atomicOr(&tmask[v], 16u<<d);
            par[w]=(unsigned short)v;
          }
        }
      }
      __syncthreads();
    }
  }
  if (tid==0){ par[0]=0; dpos[0]=0; ctr[3]=0; }
  __syncthreads();
  for (int k=0;k<36;k++){
    int a=k*256+tid;
    int v=a>>2, d=a&3;
    unsigned mv=tmask[v];
    if (((mv>>d)&1u) && ((mv>>(4+d))&1u)){
      int w=v+dstep(d);
      int S=(int)(pk[a]&0x3FFFu)-8192;
      int dep=1-S;
      dpos[w]=(unsigned short)dep;
      atomicMax(&ctr[3],dep);
    }
  }
  __syncthreads();
  int nlv_=ctr[3]+1;
  for (int i=tid;i<nlv_;i+=256) hist[i]=0;
  __syncthreads();
  for (int i=tid;i<NN;i+=256) atomicAdd(&hist[dpos[i]],1);
  __syncthreads();
  if (tid==0){
    int run=0;
    for (int l=0;l<nlv_;l++){ int c2=hist[l]; hist[l]=run; lvlstart[b*(NN+2)+l]=run; run+=c2; }
    lvlstart[b*(NN+2)+nlv_]=run;
    nlvl[b]=nlv_;
  }
  __syncthreads();
  for (int i=tid;i<NN;i+=256){
    int pos=atomicAdd(&hist[dpos[i]],1);
    lvlorder[b*NN+pos]=i;
    dpos[i]=(unsigned short)pos;
  }
  __syncthreads();
  for (int i=tid;i<NN;i+=256)
    parpos_g[b*NN + dpos[i]] = dpos[par[i]];
}

// ---------------- bf16 MFMA GEMM body, 128x128 tile, BK=32 reg-staged (proven) ----------------
// EPI 0: silu-split. EPI 1: dense residual-add (f32). EPI 2: gelu.
// EPI 3: bout0[row] = bf16(addin_f32[grow] + acc)  (gather residual, bf16 out)
// EPI 4: fout[grow] = b2f(bout1[row]) + acc        (scatter out, bf16 addin)
template<int EPI>
__device__ void gemm_body(unsigned short* lA, unsigned short* lB, int bm, int bn,
    const unsigned short* __restrict__ A, const unsigned short* __restrict__ BT,
    const float* __restrict__ bias, int Ndim, int K,
    const float* __restrict__ addin, float* __restrict__ fout,
    unsigned short* __restrict__ bout0, unsigned short* __restrict__ bout1,
    const int* __restrict__ lvl)
{
  int tid=threadIdx.x, wid=tid>>6, lane=tid&63;
  const unsigned short* Ab = A + (size_t)bm*128*K;
  const unsigned short* Bb = BT + (size_t)bn*128*K;
  int wr=wid>>1, wc=wid&1;
  f32x4 acc[4][4];
  #pragma unroll
  for (int m2=0;m2<4;m2++)
    #pragma unroll
    for (int n2=0;n2<4;n2++)
      #pragma unroll
      for (int j=0;j<4;j++) acc[m2][n2][j]=0.f;
  int r0 = tid>>2, c0 = (tid&3)*8;
  for (int k0=0;k0<K;k0+=32){
    int4 va0 = *(const int4*)(Ab + (size_t)r0*K + k0 + c0);
    int4 va1 = *(const int4*)(Ab + (size_t)(r0+64)*K + k0 + c0);
    int4 vb0 = *(const int4*)(Bb + (size_t)r0*K + k0 + c0);
    int4 vb1 = *(const int4*)(Bb + (size_t)(r0+64)*K + k0 + c0);
    __syncthreads();
    *(int4*)(lA + r0*32 + c0) = va0;
    *(int4*)(lA + (r0+64)*32 + c0) = va1;
    *(int4*)(lB + r0*32 + c0) = vb0;
    *(int4*)(lB + (r0+64)*32 + c0) = vb1;
    __syncthreads();
    int ra = (wr<<6) + (lane&15);
    int rb = (wc<<6) + (lane&15);
    int cb = (lane>>4)<<3;
    bf16x8 af[4], bfr[4];
    #pragma unroll
    for (int m2=0;m2<4;m2++) af[m2] = *(const bf16x8*)(lA + (ra+m2*16)*32 + cb);
    #pragma unroll
    for (int n2=0;n2<4;n2++) bfr[n2] = *(const bf16x8*)(lB + (rb+n2*16)*32 + cb);
    #pragma unroll
    for (int m2=0;m2<4;m2++)
      #pragma unroll
      for (int n2=0;n2<4;n2++)
        acc[m2][n2] = __builtin_amdgcn_mfma_f32_16x16x32_bf16(af[m2], bfr[n2], acc[m2][n2], 0,0,0);
  }
  int rr = (lane>>4)<<2, cc = lane&15;
  #pragma unroll
  for (int m2=0;m2<4;m2++){
    #pragma unroll
    for (int n2=0;n2<4;n2++){
      int col = (bn<<7) + (wc<<6) + (n2<<4) + cc;
      float bs = bias[col];
      #pragma unroll
      for (int j=0;j<4;j++){
        int row = (bm<<7) + (wr<<6) + (m2<<4) + rr + j;
        float v = acc[m2][n2][j] + bs;
        if (EPI==0){
          float sv = v * (1.0f/(1.0f+expf(-v)));
          if (col < DI) bout0[(size_t)row*DI + col] = f2b(sv);
          else          bout1[(size_t)row*DI + col - DI] = f2b(sv);
        } else if (EPI==1){
          size_t oi=(size_t)row*Ndim+col;
          fout[oi] = addin[oi] + v;
        } else if (EPI==2){
          size_t oi=(size_t)row*Ndim+col;
          bout0[oi] = f2b(0.5f*v*(1.0f+erff(v*0.70710678118f)));
        } else if (EPI==3){
          int grow = (row/NN)*NN + lvl[row];
          bout0[(size_t)row*Ndim+col] = f2b(addin[(size_t)grow*Ndim+col] + v);
        } else {
          int grow = (row/NN)*NN + lvl[row];
          fout[(size_t)grow*Ndim+col] = b2f(bout1[(size_t)row*Ndim+col]) + v;
        }
      }
    }
  }
}

template<int EPI>
__global__ __launch_bounds__(256) void k_gemm(
    const unsigned short* __restrict__ A, const unsigned short* __restrict__ BT,
    const float* __restrict__ bias, int Ndim, int K,
    const float* __restrict__ addin, float* __restrict__ fout,
    unsigned short* __restrict__ bout0, unsigned short* __restrict__ bout1,
    const int* __restrict__ lvl)
{
  __shared__ __align__(16) unsigned short lAB[128*32*2];
  int ntn = Ndim>>7;
  int bm = blockIdx.x/ntn, bn = blockIdx.x - bm*ntn;
  gemm_body<EPI>(lAB, lAB+128*32, bm, bn, A, BT, bias, Ndim, K, addin, fout, bout0, bout1, lvl);
}

// ---------------- fused: MST (blocks 0-15) + gemm<0> tiles ----------------
__global__ __launch_bounds__(256) void k_fused(
    const unsigned short* __restrict__ xn, const unsigned short* __restrict__ WinT,
    const float* __restrict__ b_in,
    unsigned short* __restrict__ xi_b, unsigned short* __restrict__ sz_b,
    const float* __restrict__ wgt, unsigned short* __restrict__ parpos_g,
    int* __restrict__ lvlorder, int* __restrict__ lvlstart, int* __restrict__ nlvl)
{
  __shared__ __align__(16) unsigned char smem[64528];
  if (blockIdx.x < BB){
    mst_body(smem, wgt, blockIdx.x, parpos_g, lvlorder, lvlstart, nlvl);
  } else {
    int bid = blockIdx.x - BB;
    int bm = bid>>3, bn = bid&7;
    gemm_body<0>((unsigned short*)smem, (unsigned short*)smem + 128*32, bm, bn,
                 xn, WinT, b_in, 1024, 256, nullptr, nullptr, xi_b, sz_b, nullptr);
  }
}

// ---------------- LayerNorm (bf16 input) -> bf16 ----------------
__global__ __launch_bounds__(256) void k_lnb(const unsigned short* __restrict__ xin, const float* __restrict__ g,
    const float* __restrict__ bta, unsigned short* __restrict__ outb)
{
  int row = blockIdx.x*4 + (threadIdx.x>>6); int lane=threadIdx.x&63;
  uint2 raw = *(const uint2*)(xin + (size_t)row*CC + lane*4);
  float vx=b2f((unsigned short)(raw.x&0xFFFFu)), vy=b2f((unsigned short)(raw.x>>16));
  float vz=b2f((unsigned short)(raw.y&0xFFFFu)), vw=b2f((unsigned short)(raw.y>>16));
  float s = vx+vy+vz+vw;
  #pragma unroll
  for (int o=32;o;o>>=1) s += __shfl_xor(s,o);
  float m = s*(1.0f/256.0f);
  float dx=vx-m, dy=vy-m, dz=vz-m, dw=vw-m;
  float ss=dx*dx+dy*dy+dz*dz+dw*dw;
  #pragma unroll
  for (int o=32;o;o>>=1) ss += __shfl_xor(ss,o);
  float rs = rsqrtf(ss*(1.0f/256.0f)+1e-5f);
  int cb=lane*4;
  unsigned o0 = (unsigned)f2b(dx*rs*g[cb+0]+bta[cb+0]) | ((unsigned)f2b(dy*rs*g[cb+1]+bta[cb+1])<<16);
  unsigned o1 = (unsigned)f2b(dz*rs*g[cb+2]+bta[cb+2]) | ((unsigned)f2b(dw*rs*g[cb+3]+bta[cb+3])<<16);
  *(uint2*)(outb + (size_t)row*CC + cb) = make_uint2(o0,o1);
}

// ---------------- dbc = xi @ W_xp (18 cols), ILP-parallel butterfly ----------------
__global__ __launch_bounds__(256) void k_dbc(const unsigned short* __restrict__ xi_b,
    const float* __restrict__ WxpT, float* __restrict__ dbc)
{
  int row = blockIdx.x*4 + (threadIdx.x>>6); int lane=threadIdx.x&63;
  int4 raw = *(const int4*)(xi_b + (size_t)row*DI + lane*8);
  float xf[8];
  xf[0]=b2f((unsigned short)((unsigned)raw.x&0xFFFFu)); xf[1]=b2f((unsigned short)((unsigned)raw.x>>16));
  xf[2]=b2f((unsigned short)((unsigned)raw.y&0xFFFFu)); xf[3]=b2f((unsigned short)((unsigned)raw.y>>16));
  xf[4]=b2f((unsigned short)((unsigned)raw.z&0xFFFFu)); xf[5]=b2f((unsigned short)((unsigned)raw.z>>16));
  xf[6]=b2f((unsigned short)((unsigned)raw.w&0xFFFFu)); xf[7]=b2f((unsigned short)((unsigned)raw.w>>16));
  float s[18];
  #pragma unroll
  for (int jc=0;jc<18;jc++){
    const float* wr_ = WxpT + (size_t)jc*DI + lane*8;
    float t=0.f;
    #pragma unroll
    for (int q=0;q<8;q++) t += xf[q]*wr_[q];
    s[jc]=t;
  }
  #pragma unroll
  for (int o=32;o;o>>=1){
    #pragma unroll
    for (int jc=0;jc<18;jc++) s[jc] += __shfl_xor(s[jc],o);
  }
  #pragma unroll
  for (int jc=0;jc<18;jc++)
    if (lane==jc) dbc[(size_t)row*18+jc]=s[jc];
}

// ---------------- dt/softplus -> decay/Bx, position-grouped, CHANNEL-MAJOR out ----------------
__global__ __launch_bounds__(512) void k_dbx(const float* __restrict__ dbc, const unsigned short* __restrict__ xi_b,
  const float* __restrict__ W_dt, const float* __restrict__ b_dt, const float* __restrict__ A_log,
  const int* __restrict__ lvlorder,
  unsigned short* __restrict__ dec_cm, unsigned short* __restrict__ bx_cm)
{
  __shared__ int smap[32];
  __shared__ float sd[32][18];
  int c = threadIdx.x;
  int b = blockIdx.x/72, pg = blockIdx.x - b*72;
  int p0 = pg*32;
  if (c<32) smap[c] = b*NN + lvlorder[b*NN + p0 + c];
  __syncthreads();
  for (int i=c;i<32*18;i+=512){ int rr=i/18, q=i-rr*18; sd[rr][q]=dbc[(size_t)smap[rr]*18+q]; }
  __syncthreads();
  float wdt[16];
  #pragma unroll
  for (int r2=0;r2<16;r2++) wdt[r2]=W_dt[r2*DI+c];
  float bd=b_dt[c];
  float nA=-expf(A_log[c]);
  unsigned decp[16], bxp[16];
  #pragma unroll
  for (int rr=0;rr<32;rr++){
    float a=bd;
    #pragma unroll
    for (int r2=0;r2<16;r2++) a += sd[rr][r2]*wdt[r2];
    float dt = (a>20.f)? a : log1pf(expf(a));
    float dec = expf(dt*nA);
    float bx = dt*sd[rr][16]*b2f(xi_b[(size_t)smap[rr]*DI + c]);
    if (rr&1){ decp[rr>>1] |= ((unsigned)f2b(dec))<<16; bxp[rr>>1] |= ((unsigned)f2b(bx))<<16; }
    else     { decp[rr>>1]  =  (unsigned)f2b(dec);      bxp[rr>>1]  =  (unsigned)f2b(bx); }
  }
  size_t chb = ((size_t)b*DI + c)*NN + p0;
  uint4* dp = (uint4*)(dec_cm + chb);
  uint4* bp = (uint4*)(bx_cm + chb);
  #pragma unroll
  for (int q=0;q<4;q++){
    uint4 dv, bv;
    dv.x=decp[q*4+0]; dv.y=decp[q*4+1]; dv.z=decp[q*4+2]; dv.w=decp[q*4+3];
    bv.x=bxp[q*4+0];  bv.y=bxp[q*4+1];  bv.z=bxp[q*4+2];  bv.w=bxp[q*4+3];
    dp[q]=dv; bp[q]=bv;
  }
}

// ---------------- tree scan in position space, channel-major, h in place over bx ----------------
#define SCH 4
__global__ __launch_bounds__(256) void k_scan(const unsigned short* __restrict__ dec_cm,
    unsigned short* __restrict__ bx_cm,
    const unsigned short* __restrict__ parpos_g,
    const int* __restrict__ lvlstart, const int* __restrict__ nlvl)
{
  __shared__ unsigned short sdec[SCH*NN];
  __shared__ unsigned short sbx[SCH*NN];
  __shared__ unsigned short spp[NN];
  int b = blockIdx.x>>7, t = blockIdx.x&127;
  int c0 = t*SCH;
  int tid = threadIdx.x;
  const size_t gch = ((size_t)b*DI + c0)*NN;
  #pragma unroll
  for (int cc=0;cc<SCH;cc++){
    const uint2* gd = (const uint2*)(dec_cm + gch + (size_t)cc*NN);
    const uint2* gb = (const uint2*)(bx_cm + gch + (size_t)cc*NN);
    uint2* ld = (uint2*)(sdec + cc*NN);
    uint2* lb = (uint2*)(sbx + cc*NN);
    for (int i=tid;i<NN/4;i+=256){ ld[i]=gd[i]; lb[i]=gb[i]; }
  }
  for (int i=tid;i<NN;i+=256) spp[i]=parpos_g[b*NN+i];
  int nlv = nlvl[b];
  __syncthreads();
  for (int lvl=1; lvl<nlv; lvl++){
    int s=lvlstart[b*(NN+2)+lvl], e=lvlstart[b*(NN+2)+lvl+1];
    int tot=(e-s)*SCH;
    for (int idx=tid; idx<tot; idx+=256){
      int p = s + (idx>>2);
      int cc = idx&3;
      int pp = spp[p];
      float hv = b2f(sdec[cc*NN+p])*b2f(sbx[cc*NN+pp]) + b2f(sbx[cc*NN+p]);
      sbx[cc*NN+p] = f2b(hv);
    }
    __syncthreads();
  }
  #pragma unroll
  for (int cc=0;cc<SCH;cc++){
    uint2* gb = (uint2*)(bx_cm + gch + (size_t)cc*NN);
    const uint2* lb = (const uint2*)(sbx + cc*NN);
    for (int i=tid;i<NN/4;i+=256) gb[i]=lb[i];
  }
}

// ---------------- u = (Cv*h + Dp*xi)*silu_z -> u_perm [pos][512] ----------------
__global__ __launch_bounds__(512) void k_u(const unsigned short* __restrict__ h_cm,
    const unsigned short* __restrict__ xi_b, const unsigned short* __restrict__ sz_b,
    const float* __restrict__ dbc, const float* __restrict__ Dp,
    const int* __restrict__ lvlorder, unsigned short* __restrict__ u_perm)
{
  __shared__ int smap[32];
  __shared__ unsigned short hT[32*512];
  int c = threadIdx.x;
  int b = blockIdx.x/72, pg = blockIdx.x - b*72;
  int p0 = pg*32;
  if (c<32) smap[c] = b*NN + lvlorder[b*NN + p0 + c];
  {
    const uint4* gh = (const uint4*)(h_cm + ((size_t)b*DI + c)*NN + p0);
    #pragma unroll
    for (int q=0;q<4;q++){
      uint4 w = gh[q];
      unsigned ws[4] = {w.x,w.y,w.z,w.w};
      #pragma unroll
      for (int e=0;e<4;e++){
        hT[(q*8+e*2+0)*512 + c] = (unsigned short)(ws[e]&0xFFFFu);
        hT[(q*8+e*2+1)*512 + c] = (unsigned short)(ws[e]>>16);
      }
    }
  }
  float dpc = Dp[c];
  __syncthreads();
  #pragma unroll 4
  for (int rr=0;rr<32;rr++){
    int grow = smap[rr];
    float Cv = dbc[(size_t)grow*18+17];
    float xiv = b2f(xi_b[(size_t)grow*DI + c]);
    float szv = b2f(sz_b[(size_t)grow*DI + c]);
    float hv = b2f(hT[rr*512 + c]);
    float u = (Cv*hv + dpc*xiv)*szv;
    u_perm[((size_t)(b*NN + p0 + rr))*DI + c] = f2b(u);
  }
}

// ---------------- launch ----------------
extern "C" void kernel_launch(void* const* d_in, const int* in_sizes, int n_in,
                              void* d_out, int out_size, void* d_ws, size_t ws_size,
                              hipStream_t stream) {
  (void)in_sizes; (void)n_in; (void)out_size; (void)ws_size;
  const float* x      = (const float*)d_in[0];
  const float* n1w    = (const float*)d_in[1];
  const float* n1b    = (const float*)d_in[2];
  const float* n2w    = (const float*)d_in[3];
  const float* n2b    = (const float*)d_in[4];
  const float* W_in   = (const float*)d_in[5];
  const float* b_in   = (const float*)d_in[6];
  const float* W_xp   = (const float*)d_in[7];
  const float* W_dt   = (const float*)d_in[8];
  const float* b_dt   = (const float*)d_in[9];
  const float* A_log  = (const float*)d_in[10];
  const float* Dp     = (const float*)d_in[11];
  const float* W_out  = (const float*)d_in[12];
  const float* b_out  = (const float*)d_in[13];
  const float* fc1_w  = (const float*)d_in[14];
  const float* fc1_b  = (const float*)d_in[15];
  const float* fc2_w  = (const float*)d_in[16];
  const float* fc2_b  = (const float*)d_in[17];

  char* base=(char*)d_ws; size_t off=0;
  auto alc=[&](size_t nb)->char*{ char* p=base+off; off=(off+nb+255)&~(size_t)255; return p; };
  float* wgt            = (float*)alc((size_t)MM*4*4);
  float* innorm         = (float*)alc((size_t)MM*4);
  unsigned short* parpos= (unsigned short*)alc((size_t)MM*2);
  int* lvlorder         = (int*)alc((size_t)MM*4);
  int* lvlstart         = (int*)alc((size_t)BB*(NN+2)*4);
  int* nlvl             = (int*)alc((size_t)BB*4);
  unsigned short* xi_b  = (unsigned short*)alc((size_t)MM*DI*2);
  unsigned short* sz_b  = (unsigned short*)alc((size_t)MM*DI*2);
  float* dbc            = (float*)alc((size_t)MM*18*4);
  unsigned short* dec_cm= (unsigned short*)alc((size_t)MM*DI*2);
  unsigned short* bx_cm = (unsigned short*)alc((size_t)MM*DI*2);
  unsigned short* WinT  = (unsigned short*)alc((size_t)CC*1024*2);
  unsigned short* WoutT = (unsigned short*)alc((size_t)DI*CC*2);
  unsigned short* fc1T  = (unsigned short*)alc((size_t)CC*1024*2);
  unsigned short* fc2T  = (unsigned short*)alc((size_t)1024*CC*2);
  float* WxpT           = (float*)alc((size_t)DI*18*4);
  // lifetime aliases:
  unsigned short* xn      = (unsigned short*)dec_cm; // dead before k_dbx writes dec_cm
  unsigned short* h_cm    = bx_cm;                   // scan output in place
  unsigned short* u_perm  = dec_cm;                  // dec dead after k_scan
  unsigned short* x2b     = bx_cm;                   // [MM][256] bf16; h dead after k_u
  unsigned short* x2n_perm= dec_cm;                  // u_perm dead after gemm<3>
  unsigned short* g1_perm = xi_b;                    // spans xi_b+sz_b, dead after k_u

  k_prep<<<dim3(3620),dim3(256),0,stream>>>(W_in, W_out, fc1_w, fc2_w, W_xp,
                                            WinT, WoutT, fc1T, fc2T, WxpT);
  k_normln<<<dim3(MM/4),dim3(256),0,stream>>>(x, n1w, n1b, innorm, xn);
  k_edge<<<dim3(MM/4),dim3(256),0,stream>>>(x, innorm, wgt);

  k_fused<<<dim3(BB + 288*8),dim3(256),0,stream>>>(xn, WinT, b_in, xi_b, sz_b,
                                                   wgt, parpos, lvlorder, lvlstart, nlvl);

  k_dbc<<<dim3(MM/4),dim3(256),0,stream>>>(xi_b, WxpT, dbc);
  k_dbx<<<dim3(MM/32),dim3(512),0,stream>>>(dbc, xi_b, W_dt, b_dt, A_log, lvlorder, dec_cm, bx_cm);
  k_scan<<<dim3(BB*128),dim3(256),0,stream>>>(dec_cm, bx_cm, parpos, lvlstart, nlvl);
  k_u<<<dim3(MM/32),dim3(512),0,stream>>>(h_cm, xi_b, sz_b, dbc, Dp, lvlorder, u_perm);

  k_gemm<3><<<dim3(288*2),dim3(256),0,stream>>>(u_perm, WoutT, b_out, 256, 512,
                                                x, nullptr, x2b, nullptr, lvlorder);
  k_lnb<<<dim3(MM/4),dim3(256),0,stream>>>(x2b, n2w, n2b, x2n_perm);
  k_gemm<2><<<dim3(288*8),dim3(256),0,stream>>>(x2n_perm, fc1T, fc1_b, 1024, 256,
                                                nullptr, nullptr, g1_perm, nullptr, nullptr);
  k_gemm<4><<<dim3(288*2),dim3(256),0,stream>>>(g1_perm, fc2T, fc2_b, 256, 1024,
                                                nullptr, (float*)d_out, nullptr, x2b, lvlorder);
}